// Round 1
// 291.627 us; speedup vs baseline: 1.0120x; 1.0120x over previous
//
#include <hip/hip_runtime.h>
#include <hip/hip_bf16.h>

#define B_   2
#define S_   2048
#define DM   1024
#define NH   16
#define DKH  64
#define Mdim 4096
#define Ndim 1024
#define Kdim 1024

typedef __attribute__((ext_vector_type(8))) short bf16x8;
typedef __attribute__((ext_vector_type(4))) short bf16x4;
typedef __attribute__((ext_vector_type(4))) float f32x4;

__device__ __forceinline__ short f2b(float x) {
  union { __hip_bfloat16 h; short s; } u;
  u.h = __float2bfloat16(x);
  return u.s;
}

// async global->LDS, 16 B/lane; LDS dst = wave-uniform base + lane*16
__device__ __forceinline__ void async_copy16(const void* g, void* l) {
  __builtin_amdgcn_global_load_lds(
      (const __attribute__((address_space(1))) unsigned int*)g,
      (__attribute__((address_space(3))) unsigned int*)l, 16, 0, 0);
}

// ---------------------------------------------------------------------------
// Batched fp32 -> bf16 conversion (7 tensors, one launch).
struct Cvt7 {
  const float* src[7];
  ushort* dst[7];
  int n[7];
};

__global__ __launch_bounds__(256) void cvt_all(Cvt7 c) {
  const int ten = blockIdx.y;
  const int base = (blockIdx.x * 256 + threadIdx.x) * 8;
  if (base >= c.n[ten]) return;
  const float* s = c.src[ten] + base;
  float4 a = *(const float4*)s;
  float4 b = *(const float4*)(s + 4);
  bf16x8 r;
  r[0] = f2b(a.x); r[1] = f2b(a.y); r[2] = f2b(a.z); r[3] = f2b(a.w);
  r[4] = f2b(b.x); r[5] = f2b(b.y); r[6] = f2b(b.z); r[7] = f2b(b.w);
  *(bf16x8*)(c.dst[ten] + base) = r;
}

// ---------------------------------------------------------------------------
// Pack int32 mask -> 1 bit/key. Coalesced: lane i reads one int, wave ballot
// builds the 64-bit word. mb[(b*S + q)*32 + k/64], bit j = key k/64*64+j.
__global__ __launch_bounds__(256) void mask_bits(const int* __restrict__ m,
                                                 unsigned long long* __restrict__ mb) {
  const size_t i = (size_t)blockIdx.x * 256 + threadIdx.x;
  const unsigned long long bits = __ballot(m[i] != 0);
  if ((threadIdx.x & 63) == 0) mb[i >> 6] = bits;
}

// ---------------------------------------------------------------------------
__device__ __forceinline__ void gstore(float* C, size_t i, float v) { C[i] = v; }
__device__ __forceinline__ void gstore(ushort* C, size_t i, float v) { C[i] = (ushort)f2b(v); }

// m97-structure core: C[4096,1024] = A@W^T + bias, *scale. 128x128 tile,
// BK=32, LDS via global_load_lds(16B). 4 waves 2x2; wave = 64x64 (4x4 frags).
// vt=1: write head-transposed [b][h][d][s] (for V).
template <typename OutT>
__device__ __forceinline__ void gemm_core(const ushort* __restrict__ A,
                                          const ushort* __restrict__ W,
                                          const float* __restrict__ bias,
                                          OutT* __restrict__ C, float scale, int vt,
                                          ushort* a_s, ushort* b_s) {
  const int t = threadIdx.x;
  const int w = t >> 6, lane = t & 63;
  const int quad = lane >> 4, r16 = lane & 15;
  const int wr = w >> 1, wc = w & 1;
  const int row0 = blockIdx.x * 128, col0 = blockIdx.y * 128;

  // staging: thread t -> row t>>2 (+64 for round 2), 8-elem chunk (t&3)*8
  const int sr = t >> 2, sc = (t & 3) * 8;
  const ushort* Ag0 = A + (size_t)(row0 + sr) * Kdim + sc;
  const ushort* Ag1 = Ag0 + (size_t)64 * Kdim;
  const ushort* Wg0 = W + (size_t)(col0 + sr) * Kdim + sc;
  const ushort* Wg1 = Wg0 + (size_t)64 * Kdim;
  ushort* al0 = a_s + (w * 16) * 32;        // wave-uniform; HW adds lane*16B
  ushort* al1 = a_s + (64 + w * 16) * 32;
  ushort* bl0 = b_s + (w * 16) * 32;
  ushort* bl1 = b_s + (64 + w * 16) * 32;

  f32x4 acc[4][4];
#pragma unroll
  for (int mt = 0; mt < 4; ++mt)
#pragma unroll
    for (int nt = 0; nt < 4; ++nt) acc[mt][nt] = (f32x4){0.f, 0.f, 0.f, 0.f};

  for (int k0 = 0; k0 < Kdim; k0 += 32) {
    __syncthreads();  // previous iteration's ds_reads complete
    async_copy16(Ag0 + k0, al0);
    async_copy16(Ag1 + k0, al1);
    async_copy16(Wg0 + k0, bl0);
    async_copy16(Wg1 + k0, bl1);
    __syncthreads();  // staging visible (vmcnt drain)

    bf16x8 af[4], bfr[4];
#pragma unroll
    for (int mt = 0; mt < 4; ++mt)
      af[mt] = *(const bf16x8*)&a_s[(wr * 64 + mt * 16 + r16) * 32 + quad * 8];
#pragma unroll
    for (int nt = 0; nt < 4; ++nt)
      bfr[nt] = *(const bf16x8*)&b_s[(wc * 64 + nt * 16 + r16) * 32 + quad * 8];
#pragma unroll
    for (int mt = 0; mt < 4; ++mt)
#pragma unroll
      for (int nt = 0; nt < 4; ++nt)
        acc[mt][nt] = __builtin_amdgcn_mfma_f32_16x16x32_bf16(af[mt], bfr[nt],
                                                              acc[mt][nt], 0, 0, 0);
  }

  // epilogue: C/D layout col=lane&15, row=quad*4+reg
#pragma unroll
  for (int mt = 0; mt < 4; ++mt) {
#pragma unroll
    for (int nt = 0; nt < 4; ++nt) {
      const int col = col0 + wc * 64 + nt * 16 + r16;
      const float bv = bias[col];
      const int rowb = row0 + wr * 64 + mt * 16 + quad * 4;
#pragma unroll
      for (int i = 0; i < 4; ++i) {
        const float v = (acc[mt][nt][i] + bv) * scale;
        if (vt) {
          const int row = rowb + i;
          const int bb = row >> 11, ss = row & (S_ - 1);   // row = b*S + s
          const int hh = col >> 6, dd = col & 63;          // col = h*64 + d
          gstore(C, (((size_t)bb * NH + hh) * 64 + dd) * S_ + ss, v);
        } else {
          gstore(C, (size_t)(rowb + i) * Ndim + col, v);
        }
      }
    }
  }
}

// Q/K/V projections batched in one launch (z selects) -> 768 blocks = 3/CU.
struct G3 {
  const ushort* A[3];
  const ushort* W[3];
  const float* bias[3];
  ushort* C[3];
  float scale[3];
};

__global__ __launch_bounds__(256) void gemm_qkv(G3 g) {
  __shared__ alignas(16) ushort a_s[128 * 32];
  __shared__ alignas(16) ushort b_s[128 * 32];
  const int z = blockIdx.z;
  gemm_core<ushort>(g.A[z], g.W[z], g.bias[z], g.C[z], g.scale[z], z == 2, a_s, b_s);
}

// ---------------------------------------------------------------------------
// O projection: 128x64 tile, BK=32 (512 blocks = 2/CU; better residency than
// a lone 256-block 128x128 launch).
template <typename OutT, int VT>
__global__ __launch_bounds__(256) void gemm128(const ushort* __restrict__ A,
                                               const ushort* __restrict__ W,
                                               const float* __restrict__ bias,
                                               OutT* __restrict__ C, float scale) {
  const int t = threadIdx.x;
  const int w = t >> 6, lane = t & 63;
  const int quad = lane >> 4, r16 = lane & 15;
  const int wr = w >> 1, wc = w & 1;
  const int row0 = blockIdx.x * 128, col0 = blockIdx.y * 64;

  __shared__ alignas(16) ushort a_s[128 * 32];  // [row][k]
  __shared__ alignas(16) ushort b_s[64 * 32];   // [col][k]

  const int sr = lane >> 2, sc = (lane & 3) * 8;
  const ushort* Ag0 = A + (size_t)(row0 + w * 32 + sr) * Kdim + sc;
  const ushort* Ag1 = Ag0 + (size_t)16 * Kdim;
  const ushort* Wg  = W + (size_t)(col0 + w * 16 + sr) * Kdim + sc;
  ushort* al0 = &a_s[(w * 32) * 32];
  ushort* al1 = &a_s[(w * 32 + 16) * 32];
  ushort* bl  = &b_s[(w * 16) * 32];

  f32x4 acc[4][2];
#pragma unroll
  for (int mt = 0; mt < 4; ++mt)
#pragma unroll
    for (int nt = 0; nt < 2; ++nt) acc[mt][nt] = (f32x4){0.f, 0.f, 0.f, 0.f};

  for (int k0 = 0; k0 < Kdim; k0 += 32) {
    __syncthreads();
    async_copy16(Ag0 + k0, al0);
    async_copy16(Ag1 + k0, al1);
    async_copy16(Wg + k0, bl);
    __syncthreads();

    bf16x8 af[4], bfr[2];
#pragma unroll
    for (int mt = 0; mt < 4; ++mt)
      af[mt] = *(const bf16x8*)&a_s[(wr * 64 + mt * 16 + r16) * 32 + quad * 8];
#pragma unroll
    for (int nt = 0; nt < 2; ++nt)
      bfr[nt] = *(const bf16x8*)&b_s[(wc * 32 + nt * 16 + r16) * 32 + quad * 8];
#pragma unroll
    for (int mt = 0; mt < 4; ++mt)
#pragma unroll
      for (int nt = 0; nt < 2; ++nt)
        acc[mt][nt] = __builtin_amdgcn_mfma_f32_16x16x32_bf16(af[mt], bfr[nt],
                                                              acc[mt][nt], 0, 0, 0);
  }

#pragma unroll
  for (int mt = 0; mt < 4; ++mt) {
#pragma unroll
    for (int nt = 0; nt < 2; ++nt) {
      const int col = col0 + wc * 32 + nt * 16 + r16;
      const float bv = bias[col];
      const int rowb = row0 + wr * 64 + mt * 16 + quad * 4;
#pragma unroll
      for (int i = 0; i < 4; ++i) {
        const float v = (acc[mt][nt][i] + bv) * scale;
        if (VT) {
          const int row = rowb + i;
          const int bb = row >> 11, ss = row & (S_ - 1);
          const int hh = col >> 6, dd = col & 63;
          gstore(C, (((size_t)bb * NH + hh) * 64 + dd) * S_ + ss, v);
        } else {
          gstore(C, (size_t)(rowb + i) * Ndim + col, v);
        }
      }
    }
  }
}

// ---------------------------------------------------------------------------
// MFMA flash attention, no-max softmax. Q pre-scaled by 0.125*log2(e), so
// p = exp2(s). Mask consumed as 1-bit/key words (mb). K/V staged via
// register prefetch (issue next tile's loads right after the staging barrier
// so HBM latency hides under QK^T+softmax+PV — T14).
__global__ __launch_bounds__(256) void attn_mfma(const ushort* __restrict__ Qp,
                                                 const ushort* __restrict__ Kp,
                                                 const ushort* __restrict__ Vt,
                                                 const unsigned long long* __restrict__ mb,
                                                 ushort* __restrict__ Oa) {
  const int bh = blockIdx.y;
  const int b = bh >> 4, h = bh & 15;
  const int q0 = blockIdx.x * 64;
  const int t = threadIdx.x;
  const int w = t >> 6, lane = t & 63, quad = lane >> 4, r16 = lane & 15;
  const size_t rb = (size_t)b * S_;

  // k_s:[key][dk], vt_s:[dk][key]; 8-chunks XOR-swizzled: chunk' = c ^ (row&7)
  __shared__ alignas(16) ushort k_s[64 * 64];
  __shared__ alignas(16) ushort vt_s[64 * 64];
  __shared__ alignas(16) ushort p_s[4][16 * 76];

  // Q fragment (A-layout: m=lane&15, k=quad*8+j)
  const ushort* qptr = Qp + (rb + q0 + w * 16 + r16) * DM + h * 64 + quad * 8;
  const bf16x8 aq0 = *(const bf16x8*)qptr;
  const bf16x8 aq1 = *(const bf16x8*)(qptr + 32);

  // mask bit-words: row stride 32 words; 4 rows (quad*4+i) per lane group
  const unsigned long long* mrow =
      mb + ((size_t)b * S_ + q0 + w * 16 + quad * 4) * (S_ >> 6);

  float l_i[4] = {0.f, 0.f, 0.f, 0.f};
  f32x4 oacc[4];
#pragma unroll
  for (int nt = 0; nt < 4; ++nt) oacc[nt] = (f32x4){0.f, 0.f, 0.f, 0.f};

  const int srow = t >> 3, schunk = t & 7;  // staging: 2 rounds of 32 rows
  const ushort* kbase = Kp + (rb + srow) * DM + h * 64 + schunk * 8;
  const ushort* vbase = Vt + ((size_t)bh * 64 + srow) * S_ + schunk * 8;
  const int srow2 = srow + 32;

  // prologue: prefetch tile kt=0 into registers
  bf16x8 kr0 = *(const bf16x8*)(kbase);
  bf16x8 kr1 = *(const bf16x8*)(kbase + (size_t)32 * DM);
  bf16x8 vr0 = *(const bf16x8*)(vbase);
  bf16x8 vr1 = *(const bf16x8*)(vbase + (size_t)32 * S_);

  for (int kt = 0; kt < S_; kt += 64) {
    __syncthreads();  // all waves done reading LDS from previous iteration
    *(bf16x8*)&k_s[srow * 64 + ((schunk ^ (srow & 7)) * 8)] = kr0;
    *(bf16x8*)&k_s[srow2 * 64 + ((schunk ^ (srow2 & 7)) * 8)] = kr1;
    *(bf16x8*)&vt_s[srow * 64 + ((schunk ^ (srow & 7)) * 8)] = vr0;
    *(bf16x8*)&vt_s[srow2 * 64 + ((schunk ^ (srow2 & 7)) * 8)] = vr1;
    __syncthreads();  // staging visible

    // issue NEXT tile's global loads now; latency hides under compute (T14)
    const int ktn = kt + 64;
    if (ktn < S_) {
      kr0 = *(const bf16x8*)(kbase + (size_t)ktn * DM);
      kr1 = *(const bf16x8*)(kbase + (size_t)(ktn + 32) * DM);
      vr0 = *(const bf16x8*)(vbase + ktn);
      vr1 = *(const bf16x8*)(vbase + (size_t)32 * S_ + ktn);
    }

    // mask words for this key-tile (1 uint64 per q-row; L1/L2-resident)
    const int kw = kt >> 6;
    unsigned long long mw4[4];
#pragma unroll
    for (int i = 0; i < 4; ++i) mw4[i] = mrow[(size_t)i * (S_ >> 6) + kw];

    // ---- S = Q K^T (16 q-rows x 64 keys per wave)
    bf16x8 kf[8];
#pragma unroll
    for (int nt = 0; nt < 4; ++nt) {
      const int krow = nt * 16 + r16;
      kf[2 * nt]     = *(const bf16x8*)&k_s[krow * 64 + ((quad ^ (krow & 7)) * 8)];
      kf[2 * nt + 1] = *(const bf16x8*)&k_s[krow * 64 + (((4 + quad) ^ (krow & 7)) * 8)];
    }
    f32x4 sacc[4];
    __builtin_amdgcn_s_setprio(1);
#pragma unroll
    for (int nt = 0; nt < 4; ++nt) {
      sacc[nt] = (f32x4){0.f, 0.f, 0.f, 0.f};
      sacc[nt] = __builtin_amdgcn_mfma_f32_16x16x32_bf16(aq0, kf[2 * nt], sacc[nt], 0, 0, 0);
      sacc[nt] = __builtin_amdgcn_mfma_f32_16x16x32_bf16(aq1, kf[2 * nt + 1], sacc[nt], 0, 0, 0);
    }
    __builtin_amdgcn_s_setprio(0);

    // ---- mask (bit test) + exp2 (Q carries log2e)
#pragma unroll
    for (int i = 0; i < 4; ++i) {
      const unsigned mlo = (unsigned)mw4[i];
      const unsigned mhi = (unsigned)(mw4[i] >> 32);
      float ps = 0.f;
#pragma unroll
      for (int nt = 0; nt < 4; ++nt) {
        const unsigned half = (nt & 2) ? mhi : mlo;
        const unsigned bit = (half >> ((nt & 1) * 16 + r16)) & 1u;
        const float p = bit ? exp2f(sacc[nt][i]) : 0.f;
        ps += p;
        p_s[w][(quad * 4 + i) * 76 + nt * 16 + r16] = (ushort)f2b(p);
      }
      l_i[i] += ps;
    }

    // ---- O += P V (P via wave-private LDS; same-wave DS ordering)
#pragma unroll
    for (int ks = 0; ks < 2; ++ks) {
      const bf16x4 lo = *(const bf16x4*)&p_s[w][r16 * 76 + ks * 32 + quad * 8];
      const bf16x4 hi = *(const bf16x4*)&p_s[w][r16 * 76 + ks * 32 + quad * 8 + 4];
      bf16x8 pa;
#pragma unroll
      for (int j = 0; j < 4; ++j) { pa[j] = lo[j]; pa[4 + j] = hi[j]; }
      const int kc = ks * 4 + quad;
      bf16x8 vb[4];
#pragma unroll
      for (int nt = 0; nt < 4; ++nt) {
        const int dk = nt * 16 + r16;
        vb[nt] = *(const bf16x8*)&vt_s[dk * 64 + ((kc ^ (dk & 7)) * 8)];
      }
      __builtin_amdgcn_s_setprio(1);
#pragma unroll
      for (int nt = 0; nt < 4; ++nt)
        oacc[nt] = __builtin_amdgcn_mfma_f32_16x16x32_bf16(pa, vb[nt], oacc[nt], 0, 0, 0);
      __builtin_amdgcn_s_setprio(0);
    }
  }

  // ---- epilogue: reduce l across the 16 lanes holding each row, divide, store
#pragma unroll
  for (int i = 0; i < 4; ++i) {
    float l = l_i[i];
#pragma unroll
    for (int off = 1; off < 16; off <<= 1) l += __shfl_xor(l, off);
    l_i[i] = l;
  }
#pragma unroll
  for (int nt = 0; nt < 4; ++nt) {
#pragma unroll
    for (int i = 0; i < 4; ++i) {
      const int row = q0 + w * 16 + quad * 4 + i;
      const int col = h * 64 + nt * 16 + r16;
      Oa[(rb + row) * DM + col] = (ushort)f2b(oacc[nt][i] / l_i[i]);
    }
  }
}

// ---------------------------------------------------------------------------
// Workspace = 56 MB exactly:
//   qc,kc,vc (3*NE u16) | Qp,Kp,Vt (3*NE u16) | 4 weights (4*NW u16)
//   attn output reuses qc; mask bit-words (1 MB) reuse vc (free after V GEMM).
extern "C" void kernel_launch(void* const* d_in, const int* in_sizes, int n_in,
                              void* d_out, int out_size, void* d_ws, size_t ws_size,
                              hipStream_t stream) {
  const int* mask = (const int*)d_in[3];
  const float* bq = (const float*)d_in[5];
  const float* bk = (const float*)d_in[7];
  const float* bv = (const float*)d_in[9];
  const float* bo = (const float*)d_in[11];

  const size_t NE = (size_t)B_ * S_ * DM;  // 4M
  const size_t NW = (size_t)DM * DM;       // 1M

  ushort* qc = (ushort*)d_ws;
  ushort* kc = qc + NE;
  ushort* vc = kc + NE;
  ushort* Qp = vc + NE;
  ushort* Kp = Qp + NE;
  ushort* Vt = Kp + NE;
  ushort* Wqc = Vt + NE;
  ushort* Wkc = Wqc + NW;
  ushort* Wvc = Wkc + NW;
  ushort* Woc = Wvc + NW;
  unsigned long long* mbits = (unsigned long long*)vc;  // 131072 words = 1 MB

  Cvt7 c;
  const int sidx[7] = {0, 1, 2, 4, 6, 8, 10};
  ushort* dsts[7] = {qc, kc, vc, Wqc, Wkc, Wvc, Woc};
  for (int i = 0; i < 7; ++i) {
    c.src[i] = (const float*)d_in[sidx[i]];
    c.dst[i] = dsts[i];
    c.n[i] = (i < 3) ? (int)NE : (int)NW;
  }
  cvt_all<<<dim3(2048, 7), 256, 0, stream>>>(c);

  // Q projection pre-scaled by (1/sqrt(dk)) * log2(e) so attn uses exp2
  G3 g;
  g.A[0] = qc;  g.A[1] = kc;  g.A[2] = vc;
  g.W[0] = Wqc; g.W[1] = Wkc; g.W[2] = Wvc;
  g.bias[0] = bq; g.bias[1] = bk; g.bias[2] = bv;
  g.C[0] = Qp;  g.C[1] = Kp;  g.C[2] = Vt;
  g.scale[0] = 0.125f * 1.4426950408889634f;
  g.scale[1] = 1.0f;
  g.scale[2] = 1.0f;
  gemm_qkv<<<dim3(Mdim / 128, Ndim / 128, 3), 256, 0, stream>>>(g);

  // pack mask into vc region (V GEMM has consumed vc by now)
  mask_bits<<<(B_ * S_ * S_) / 256, 256, 0, stream>>>(mask, mbits);

  attn_mfma<<<dim3(S_ / 64, B_ * NH), 256, 0, stream>>>(Qp, Kp, Vt, mbits, qc);

  gemm128<float, 0><<<dim3(Mdim / 128, Ndim / 64), 256, 0, stream>>>(
      qc, Woc, bo, (float*)d_out, 1.0f);
}